// Round 2
// baseline (2483.489 us; speedup 1.0000x reference)
//
#include <hip/hip_runtime.h>
#include <hip/hip_bf16.h>
#include <stdint.h>

typedef __bf16 bf16x8 __attribute__((ext_vector_type(8)));
typedef float  floatx4 __attribute__((ext_vector_type(4)));

static constexpr int kT = 512, kH = 1024, k4H = 4096;

// ---------------------------------------------------------------------------
// Weight pack: wpk[np(256)][c(64)][lane(64)][j(8)] bf16  (MFMA B-fragment order)
//   n_local = lane&15 = hl*4 + g  (gates interleaved inside each 16-wide n-tile)
//   col_W   = g*1024 + np*4 + hl ;  np = cg*4 + nt  ->  hcol = cg*16 + nt*4 + hl
//   fused k = c*32 + (lane>>4)*8 + j   (c<32: Wx rows, c>=32: Wh rows)
// ---------------------------------------------------------------------------
__global__ void pack_w(const float* __restrict__ Wx, const float* __restrict__ Wh,
                       __bf16* __restrict__ wpk) {
  int idx = blockIdx.x * 256 + threadIdx.x;          // 1,048,576 threads
  int l  = idx & 63;
  int c  = (idx >> 6) & 63;
  int np = idx >> 12;                                // 0..255
  int nl = l & 15;
  int g  = nl & 3, hl = nl >> 2;
  int col = g * kH + np * 4 + hl;
  int kf  = (l >> 4) * 8;
  const float* src = (c < 32) ? Wx + (size_t)(c * 32 + kf) * k4H + col
                              : Wh + (size_t)((c - 32) * 32 + kf) * k4H + col;
  bf16x8 v;
#pragma unroll
  for (int j = 0; j < 8; ++j) v[j] = (__bf16)src[(size_t)j * k4H];
  *(bf16x8*)(wpk + (size_t)idx * 8) = v;
}

// ---------------------------------------------------------------------------
// x pack: xpk[t][mt(4)][c(32)][lane(64)][j(8)] bf16  (MFMA A-fragment order)
//   m = mt*16 + (lane&15),  k = c*32 + (lane>>4)*8 + j
// ---------------------------------------------------------------------------
__global__ void pack_x(const float* __restrict__ x, __bf16* __restrict__ xpk) {
  int idx = blockIdx.x * 256 + threadIdx.x;          // 4,194,304 threads
  int l  = idx & 63;
  int c  = (idx >> 6) & 31;
  int mt = (idx >> 11) & 3;
  int t  = idx >> 13;
  int m  = mt * 16 + (l & 15);
  int f  = c * 32 + (l >> 4) * 8;
  const float4* src = (const float4*)(x + ((size_t)m * kT + t) * 1024 + f);
  float4 r0 = src[0], r1 = src[1];
  bf16x8 v;
  v[0] = (__bf16)r0.x; v[1] = (__bf16)r0.y; v[2] = (__bf16)r0.z; v[3] = (__bf16)r0.w;
  v[4] = (__bf16)r1.x; v[5] = (__bf16)r1.y; v[6] = (__bf16)r1.z; v[7] = (__bf16)r1.w;
  *(bf16x8*)(xpk + (size_t)idx * 8) = v;
}

// ---------------------------------------------------------------------------
// Persistent scan, 256 WGs x 512 thr (1 WG/CU). WG = (cg 0..63, mq 0..3).
//
// h exchange (sentinel-gated, PER-WAVE sentinels, no drains beyond the h-store):
//   DATA: hd ring (4 slots), packed 2xbf16/dword, agent-scope relaxed stores
//         by gate threads, read ONCE per step by consumers after detect.
//   DETECT: per-(cg,wave) sentinel dwords. Gate wave w publishes
//         sent[t&7][mq][cg][w] = t immediately after ITS OWN
//         s_waitcnt vmcnt(0) (h-stores acked at coherence point) — no
//         barrier, no coupling to other waves, and the nontemporal out
//         store is issued AFTER the sentinel so its HBM ack is never on
//         the critical path. Consumer wave s polls 64 dwords (one per
//         lane: 16 cgs x 4 waves, 4 cache lines) + s_sleep throttle.
//
// Ring margin (3 steps): WG P overwrites hd slot t&3 at step t+4 only after
// P observed sentinels for t+3 from every producer Q; Q published t+3 only
// after Q's gate at t+1, which required Q's reads of slot t&3 complete.
// Sentinel value==t is poison-safe (8-slot sentinel ring, t<512; sent
// additionally memset to 0xFF before launch).
//
// Barriers are raw s_barrier: B2 needs only lgkmcnt(0) (zbuf LDS ordering);
// B3 needs no waitcnt (all LDS reads consumed, vmem loads compiler-waited).
//
// hd layout (dwords): [slot(4)][mq(4)][hg=hcol>>3 (128)][gm(16)][d=(hcol&7)/2 (4)]
// ---------------------------------------------------------------------------
__launch_bounds__(512, 2)
__global__ void lstm_scan(const __bf16* __restrict__ xpk, const __bf16* __restrict__ wpk,
                          const float* __restrict__ bias, uint32_t* __restrict__ hd,
                          int* __restrict__ sent, float* __restrict__ out) {
  const int blk  = blockIdx.x;
  const int half = blk & 1;
  const int mq   = (blk >> 1) & 3;
  const int cg   = half * 32 + (blk >> 3);           // 0..63
  const int tid  = threadIdx.x;
  const int wave = tid >> 6;                         // 0..7
  const int lane = tid & 63;

  __shared__ __align__(16) float zbuf[8][16][68];

  // ---- persistent weight fragments: breg[ntile][chunk], chunk = wave*8+cc ----
  bf16x8 breg[4][8];
#pragma unroll
  for (int nt = 0; nt < 4; ++nt) {
    const __bf16* wsrc = wpk + (((size_t)(cg * 4 + nt) * 64 + wave * 8) * 64 + lane) * 8;
#pragma unroll
    for (int cc = 0; cc < 8; ++cc)
      breg[nt][cc] = *(const bf16x8*)(wsrc + (size_t)cc * 512);
  }
#pragma unroll
  for (int nt = 0; nt < 4; ++nt)
#pragma unroll
    for (int cc = 0; cc < 8; ++cc)
      asm volatile("" : "+v"(breg[nt][cc]));         // pin: no remat from memory

  // ---- gate-phase per-thread state (threads 0..255) ----
  const int gm   = (tid >> 4) & 15;
  const int ghc  = tid & 15;
  const int m_g  = mq * 16 + gm;
  const int hcol = cg * 16 + ghc;
  const int gnt  = ghc >> 2, ghl = ghc & 3;
  float c_state  = 0.f;
  const float bi = bias[0 * kH + hcol], bf_ = bias[1 * kH + hcol];
  const float bg = bias[2 * kH + hcol], bo  = bias[3 * kH + hcol];
  // packed-h dword index (minus slot term slot*32768)
  const int hdoff = ((mq * 128 + cg * 2 + (ghc >> 3)) * 16 + gm) * 4 + ((ghc & 7) >> 1);
  // per-wave sentinel dword (minus slot term): [mq][cg][wave]
  const int soff  = mq * 256 + cg * 4 + wave;

  floatx4 acc[4];
#pragma unroll
  for (int nt = 0; nt < 4; ++nt) acc[nt] = floatx4{0.f, 0.f, 0.f, 0.f};

  // ---- prologue: x-part of t=0 (h_{-1}=0 so h-waves contribute zero) ----
  if (wave < 4) {
    const __bf16* asrc = xpk + ((size_t)mq * 32 + wave * 8) * 512 + (size_t)lane * 8;
#pragma unroll
    for (int cc = 0; cc < 8; ++cc) {
      bf16x8 a = *(const bf16x8*)(asrc + (size_t)cc * 512);
#pragma unroll
      for (int nt = 0; nt < 4; ++nt)
        acc[nt] = __builtin_amdgcn_mfma_f32_16x16x32_bf16(a, breg[nt][cc], acc[nt], 0, 0, 0);
    }
  }

#pragma unroll 1
  for (int t = 0; t < kT; ++t) {
    // publish partials to LDS (all zbuf readers of step t-1 passed B3 already)
#pragma unroll
    for (int nt = 0; nt < 4; ++nt)
#pragma unroll
      for (int rr = 0; rr < 4; ++rr)
        zbuf[wave][(lane >> 4) * 4 + rr][nt * 16 + (lane & 15)] = acc[nt][rr];
    // B2: zbuf writes visible to all waves (LDS ordering only, no vmem drain)
    asm volatile("s_waitcnt lgkmcnt(0)" ::: "memory");
    __builtin_amdgcn_s_barrier();
    asm volatile("" ::: "memory");

    if (tid < 256) {
      float zi = bi, zf = bf_, zg = bg, zo = bo;
      const float* zp = &zbuf[0][gm][gnt * 16 + ghl * 4];
#pragma unroll
      for (int w = 0; w < 8; ++w) {
        floatx4 zv = *(const floatx4*)(zp + (size_t)w * 16 * 68);
        zi += zv[0]; zf += zv[1]; zg += zv[2]; zo += zv[3];
      }
      float ig = 1.f / (1.f + __expf(-zi));
      float fg = 1.f / (1.f + __expf(-zf));
      float gg = 2.f / (1.f + __expf(-2.f * zg)) - 1.f;
      float og = 1.f / (1.f + __expf(-zo));
      c_state = fg * c_state + ig * gg;
      float tc = 2.f / (1.f + __expf(-2.f * c_state)) - 1.f;
      float h  = og * tc;
      // --- critical path: packed h store -> own-wave drain -> own sentinel ---
      __bf16 hb16 = (__bf16)h;
      uint16_t hbits;
      __builtin_memcpy(&hbits, &hb16, 2);
      uint32_t mine = hbits;
      uint32_t partner = (uint32_t)__shfl_xor((int)mine, 1);   // ghc^1, same wave
      if ((ghc & 1) == 0) {
        uint32_t packed = mine | (partner << 16);
        __hip_atomic_store(&hd[(size_t)(t & 3) * 32768 + hdoff], packed,
                           __ATOMIC_RELAXED, __HIP_MEMORY_SCOPE_AGENT);
      }
      // drain ONLY the h-stores (out store not yet issued), then publish
      asm volatile("s_waitcnt vmcnt(0)" ::: "memory");
      if (lane == 0)
        __hip_atomic_store(&sent[(size_t)(t & 7) * 1024 + soff], t,
                           __ATOMIC_RELAXED, __HIP_MEMORY_SCOPE_AGENT);
      // out store AFTER sentinel: its HBM ack never gates the exchange
      __builtin_nontemporal_store(h, &out[((size_t)m_g * kT + t) * kH + hcol]);
    }
    // B3: protect zbuf reuse only — raw barrier, no drains
    asm volatile("" ::: "memory");
    __builtin_amdgcn_s_barrier();
    asm volatile("" ::: "memory");

    // ---- tail: partials for step t+1 ----
    if (t < kT - 1) {
#pragma unroll
      for (int nt = 0; nt < 4; ++nt) acc[nt] = floatx4{0.f, 0.f, 0.f, 0.f};
      if (wave < 4) {                                // x-part of t+1: runs ahead
        const __bf16* asrc = xpk + (((size_t)(t + 1) * 4 + mq) * 32 + wave * 8) * 512
                           + (size_t)lane * 8;
#pragma unroll
        for (int cc = 0; cc < 8; ++cc) {
          bf16x8 a = __builtin_nontemporal_load((const bf16x8*)(asrc + (size_t)cc * 512));
#pragma unroll
          for (int nt = 0; nt < 4; ++nt)
            acc[nt] = __builtin_amdgcn_mfma_f32_16x16x32_bf16(a, breg[nt][cc], acc[nt], 0, 0, 0);
        }
      } else {                                       // h-part: light poll, one-shot load
        const int s = wave - 4;
        // poll 64 sentinels: 16 cgs of this slice x 4 producer waves, 1/lane
        const int* sline = sent + (size_t)(t & 7) * 1024 + mq * 256 + s * 64 + lane;
        int guard = 0;
        for (;;) {
          int v = __hip_atomic_load(sline, __ATOMIC_RELAXED, __HIP_MEMORY_SCOPE_AGENT);
          if (__all(v == t)) break;                  // all producers of slice s done
          __builtin_amdgcn_s_sleep(2);
          if (++guard > (1 << 20)) break;            // fail loud, not hung
        }
        asm volatile("" ::: "memory");               // no hoisting data loads above poll
        const uint64_t* hb = (const uint64_t*)hd + (size_t)(t & 3) * 16384
                           + ((size_t)(mq * 128 + s * 32 + (lane >> 4)) * 16 + (lane & 15)) * 2;
        uint64_t w[8][2];
#pragma unroll
        for (int c = 0; c < 8; ++c) {
          w[c][0] = __hip_atomic_load(hb + (size_t)c * 128,     __ATOMIC_RELAXED,
                                      __HIP_MEMORY_SCOPE_AGENT);
          w[c][1] = __hip_atomic_load(hb + (size_t)c * 128 + 1, __ATOMIC_RELAXED,
                                      __HIP_MEMORY_SCOPE_AGENT);
        }
#pragma unroll
        for (int c = 0; c < 8; ++c) {
          union { uint64_t q[2]; bf16x8 v; } u;
          u.q[0] = w[c][0]; u.q[1] = w[c][1];
#pragma unroll
          for (int nt = 0; nt < 4; ++nt)
            acc[nt] = __builtin_amdgcn_mfma_f32_16x16x32_bf16(u.v, breg[nt][c], acc[nt], 0, 0, 0);
        }
      }
    }
  }
}

// ---------------------------------------------------------------------------
extern "C" void kernel_launch(void* const* d_in, const int* in_sizes, int n_in,
                              void* d_out, int out_size, void* d_ws, size_t ws_size,
                              hipStream_t stream) {
  const float* x  = (const float*)d_in[0];   // [64,512,1024]
  const float* Wx = (const float*)d_in[1];   // [1024,4096]
  const float* Wh = (const float*)d_in[2];   // [1024,4096]
  const float* b  = (const float*)d_in[3];   // [4096]
  float* out = (float*)d_out;

  char* ws = (char*)d_ws;
  int*      snt = (int*)ws;                                 // 32 KB sentinel dwords
  uint32_t* hdb = (uint32_t*)(ws + ((size_t)1 << 16));      // 512 KB packed-h ring
  __bf16*   wpk = (__bf16*)(ws + ((size_t)1 << 20));        // 16 MB
  __bf16*   xpk = (__bf16*)(ws + ((size_t)17 << 20));       // 64 MB  (total 81 MB)
  (void)in_sizes; (void)n_in; (void)out_size; (void)ws_size;

  // poison sentinels: 0xFFFFFFFF never equals a valid t < 512
  hipMemsetAsync(snt, 0xFF, (size_t)32 << 10, stream);

  hipLaunchKernelGGL(pack_w, dim3(4096),  dim3(256), 0, stream, Wx, Wh, wpk);
  hipLaunchKernelGGL(pack_x, dim3(16384), dim3(256), 0, stream, x, xpk);
  hipLaunchKernelGGL(lstm_scan, dim3(256), dim3(512), 0, stream,
                     xpk, wpk, b, hdb, snt, out);
}

// Round 3
// 2284.100 us; speedup vs baseline: 1.0873x; 1.0873x over previous
//
#include <hip/hip_runtime.h>
#include <hip/hip_bf16.h>
#include <stdint.h>

typedef __bf16 bf16x8 __attribute__((ext_vector_type(8)));
typedef float  floatx4 __attribute__((ext_vector_type(4)));

static constexpr int kT = 512, kH = 1024, k4H = 4096;

// ---------------------------------------------------------------------------
// Weight pack: wpk[np(256)][c(64)][lane(64)][j(8)] bf16  (MFMA B-fragment order)
//   n_local = lane&15 = hl*4 + g  (gates interleaved inside each 16-wide n-tile)
//   col_W   = g*1024 + np*4 + hl ;  np = cg*4 + nt  ->  hcol = cg*16 + nt*4 + hl
//   fused k = c*32 + (lane>>4)*8 + j   (c<32: Wx rows, c>=32: Wh rows)
// ---------------------------------------------------------------------------
__global__ void pack_w(const float* __restrict__ Wx, const float* __restrict__ Wh,
                       __bf16* __restrict__ wpk) {
  int idx = blockIdx.x * 256 + threadIdx.x;          // 1,048,576 threads
  int l  = idx & 63;
  int c  = (idx >> 6) & 63;
  int np = idx >> 12;                                // 0..255
  int nl = l & 15;
  int g  = nl & 3, hl = nl >> 2;
  int col = g * kH + np * 4 + hl;
  int kf  = (l >> 4) * 8;
  const float* src = (c < 32) ? Wx + (size_t)(c * 32 + kf) * k4H + col
                              : Wh + (size_t)((c - 32) * 32 + kf) * k4H + col;
  bf16x8 v;
#pragma unroll
  for (int j = 0; j < 8; ++j) v[j] = (__bf16)src[(size_t)j * k4H];
  *(bf16x8*)(wpk + (size_t)idx * 8) = v;
}

// ---------------------------------------------------------------------------
// x pack: xpk[t][mt(4)][c(32)][lane(64)][j(8)] bf16  (MFMA A-fragment order)
//   m = mt*16 + (lane&15),  k = c*32 + (lane>>4)*8 + j
// ---------------------------------------------------------------------------
__global__ void pack_x(const float* __restrict__ x, __bf16* __restrict__ xpk) {
  int idx = blockIdx.x * 256 + threadIdx.x;          // 4,194,304 threads
  int l  = idx & 63;
  int c  = (idx >> 6) & 31;
  int mt = (idx >> 11) & 3;
  int t  = idx >> 13;
  int m  = mt * 16 + (l & 15);
  int f  = c * 32 + (l >> 4) * 8;
  const float4* src = (const float4*)(x + ((size_t)m * kT + t) * 1024 + f);
  float4 r0 = src[0], r1 = src[1];
  bf16x8 v;
  v[0] = (__bf16)r0.x; v[1] = (__bf16)r0.y; v[2] = (__bf16)r0.z; v[3] = (__bf16)r0.w;
  v[4] = (__bf16)r1.x; v[5] = (__bf16)r1.y; v[6] = (__bf16)r1.z; v[7] = (__bf16)r1.w;
  *(bf16x8*)(xpk + (size_t)idx * 8) = v;
}

// ---------------------------------------------------------------------------
// Persistent scan, 256 WGs x 512 thr (1 WG/CU). WG = (cg 0..63, mq 0..3).
//
// h exchange: SELF-VALIDATING TAGGED DWORDS, no sentinel protocol at all.
//   Each gate thread stores ONE dword: { hi16 = tag = t, lo16 = bf16 h }.
//   Consumers speculatively load their slice (16 qwords = 32 tagged values
//   per lane), verify tags in-register, retry ONLY mismatched qwords.
//   No detect round-trip: the load IS the detect. B2/B3 stay __syncthreads
//   (identical to the proven baseline structure).
//
// 8-wave rebalance: every wave owns 4 x-chunks (fused k 0..1023) AND 4
// h-chunks (fused k 1024..2047). Per step each wave: x-loads+MFMA (hides
// producer->L3 propagation), then tagged h loads + verify + h-MFMA.
// Halves per-wave h-load volume vs the 4-consumer split and keeps VGPRs
// at ~80 (round 1 failed partly by capping at 128 -> spills).
//
// Ring: 4 slots. Overwrite margin (transitive, 4-deep): P writes h_{t+4}
// (slot t&3) only after P's B2(t+4), which needs P's tail(t+3) verified,
// which needs every Q published t+3, which needs Q's tail(t+2) verified,
// ... which needs every WG's tail(t) reads complete. A straggler stuck in
// tail(t) verify blocks the whole chain (its awaited tags are already
// published) -> self-throttling, no deadlock, no stale consumption.
// Ring memset 0xFF per launch: tag 0xFFFF never matches t < 512.
//
// tg layout (dwords): [slot(4)][mq(4)][hb=hcol>>3 (128)][m(16)][w=hcol&7 (8)]
//   consumer lane (chunk cc): hb = (wave*4+cc)*4 + (lane>>4), m = lane&15,
//   reads qwords {hb*64 + m*4 + 0..3} (32B contiguous per lane).
// ---------------------------------------------------------------------------
__launch_bounds__(512, 2)
__global__ void lstm_scan(const __bf16* __restrict__ xpk, const __bf16* __restrict__ wpk,
                          const float* __restrict__ bias, uint32_t* __restrict__ tg,
                          float* __restrict__ out) {
  const int blk  = blockIdx.x;
  const int half = blk & 1;
  const int mq   = (blk >> 1) & 3;
  const int cg   = half * 32 + (blk >> 3);           // 0..63
  const int tid  = threadIdx.x;
  const int wave = tid >> 6;                         // 0..7
  const int lane = tid & 63;

  __shared__ __align__(16) float zbuf[8][16][68];

  // ---- persistent weight fragments: breg[nt][cc]; cc<4 = x-chunk wave*4+cc,
  //      cc>=4 = h-chunk 32 + wave*4 + (cc-4) ----
  bf16x8 breg[4][8];
#pragma unroll
  for (int nt = 0; nt < 4; ++nt) {
    const __bf16* wnp = wpk + (size_t)(cg * 4 + nt) * 64 * 512;
#pragma unroll
    for (int cc = 0; cc < 8; ++cc) {
      int gc = (cc < 4) ? (wave * 4 + cc) : (32 + wave * 4 + (cc - 4));
      breg[nt][cc] = *(const bf16x8*)(wnp + (size_t)gc * 512 + (size_t)lane * 8);
    }
  }
#pragma unroll
  for (int nt = 0; nt < 4; ++nt)
#pragma unroll
    for (int cc = 0; cc < 8; ++cc)
      asm volatile("" : "+v"(breg[nt][cc]));         // pin: no remat from memory

  // ---- gate-phase per-thread state (threads 0..255) ----
  const int gm   = (tid >> 4) & 15;
  const int ghc  = tid & 15;
  const int m_g  = mq * 16 + gm;
  const int hcol = cg * 16 + ghc;
  const int gnt  = ghc >> 2, ghl = ghc & 3;
  float c_state  = 0.f;
  const float bi = bias[0 * kH + hcol], bf_ = bias[1 * kH + hcol];
  const float bg = bias[2 * kH + hcol], bo  = bias[3 * kH + hcol];
  // tagged-dword index (minus slot term slot*65536)
  const int tgoff = ((mq * 128 + cg * 2 + (ghc >> 3)) * 16 + gm) * 8 + (ghc & 7);

  floatx4 acc[4];
#pragma unroll
  for (int nt = 0; nt < 4; ++nt) acc[nt] = floatx4{0.f, 0.f, 0.f, 0.f};

  // ---- prologue: x-part of t=0 (h_{-1}=0), all 8 waves, 4 chunks each ----
#pragma unroll
  for (int cc = 0; cc < 4; ++cc) {
    const __bf16* asrc = xpk + ((size_t)mq * 32 + wave * 4 + cc) * 512 + (size_t)lane * 8;
    bf16x8 a = *(const bf16x8*)asrc;
#pragma unroll
    for (int nt = 0; nt < 4; ++nt)
      acc[nt] = __builtin_amdgcn_mfma_f32_16x16x32_bf16(a, breg[nt][cc], acc[nt], 0, 0, 0);
  }

#pragma unroll 1
  for (int t = 0; t < kT; ++t) {
    // publish partials to LDS (all zbuf readers of step t-1 passed B3 already)
#pragma unroll
    for (int nt = 0; nt < 4; ++nt)
#pragma unroll
      for (int rr = 0; rr < 4; ++rr)
        zbuf[wave][(lane >> 4) * 4 + rr][nt * 16 + (lane & 15)] = acc[nt][rr];
    __syncthreads();                                 // B2: zbuf complete

    if (tid < 256) {
      float zi = bi, zf = bf_, zg = bg, zo = bo;
      const float* zp = &zbuf[0][gm][gnt * 16 + ghl * 4];
#pragma unroll
      for (int w = 0; w < 8; ++w) {
        floatx4 zv = *(const floatx4*)(zp + (size_t)w * 16 * 68);
        zi += zv[0]; zf += zv[1]; zg += zv[2]; zo += zv[3];
      }
      float ig = 1.f / (1.f + __expf(-zi));
      float fg = 1.f / (1.f + __expf(-zf));
      float gg = 2.f / (1.f + __expf(-2.f * zg)) - 1.f;
      float og = 1.f / (1.f + __expf(-zo));
      c_state = fg * c_state + ig * gg;
      float tc = 2.f / (1.f + __expf(-2.f * c_state)) - 1.f;
      float h  = og * tc;
      // tagged publish FIRST (critical path), then the nt out-store
      __bf16 hb16 = (__bf16)h;
      uint16_t hbits;
      __builtin_memcpy(&hbits, &hb16, 2);
      uint32_t tagged = ((uint32_t)t << 16) | (uint32_t)hbits;
      __hip_atomic_store(&tg[(size_t)(t & 3) * 65536 + tgoff], tagged,
                         __ATOMIC_RELAXED, __HIP_MEMORY_SCOPE_AGENT);
      __builtin_nontemporal_store(h, &out[((size_t)m_g * kT + t) * kH + hcol]);
    }
    __syncthreads();                                 // B3: zbuf reuse protection

    // ---- tail: partials for step t+1 (all 8 waves: 4 x-chunks + 4 h-chunks) --
    if (t < kT - 1) {
#pragma unroll
      for (int nt = 0; nt < 4; ++nt) acc[nt] = floatx4{0.f, 0.f, 0.f, 0.f};

      // (1) x-loads for t+1 (issued first so x-MFMA never waits on h loads)
      bf16x8 xa[4];
#pragma unroll
      for (int cc = 0; cc < 4; ++cc) {
        const __bf16* asrc = xpk + (((size_t)(t + 1) * 4 + mq) * 32 + wave * 4 + cc) * 512
                           + (size_t)lane * 8;
        xa[cc] = __builtin_nontemporal_load((const bf16x8*)asrc);
      }

      // (2) speculative tagged h loads: 16 qwords/lane (32 tagged values)
      const uint64_t* tqb = (const uint64_t*)tg + (size_t)(t & 3) * 32768
                          + (size_t)mq * 8192 + (size_t)wave * 1024
                          + (size_t)(lane >> 4) * 64 + (size_t)(lane & 15) * 4;
      uint64_t q[4][4];
#pragma unroll
      for (int cc = 0; cc < 4; ++cc)
#pragma unroll
        for (int k = 0; k < 4; ++k)
          q[cc][k] = __hip_atomic_load(tqb + (size_t)cc * 256 + k,
                                       __ATOMIC_RELAXED, __HIP_MEMORY_SCOPE_AGENT);

      // (3) x-MFMA overlaps h-load latency + producer->L3 propagation
#pragma unroll
      for (int cc = 0; cc < 4; ++cc)
#pragma unroll
        for (int nt = 0; nt < 4; ++nt)
          acc[nt] = __builtin_amdgcn_mfma_f32_16x16x32_bf16(xa[cc], breg[nt][cc], acc[nt], 0, 0, 0);

      // (4) verify tags; retry only mismatched qwords
      const uint64_t pat = ((uint64_t)(uint32_t)t << 16) | ((uint64_t)(uint32_t)t << 48);
      const uint64_t msk = 0xFFFF0000FFFF0000ull;
      int guard = 0;
      for (;;) {
        uint64_t bad = 0;
#pragma unroll
        for (int cc = 0; cc < 4; ++cc)
#pragma unroll
          for (int k = 0; k < 4; ++k)
            bad |= (q[cc][k] ^ pat) & msk;
        if (__all(bad == 0)) break;
        __builtin_amdgcn_s_sleep(2);
#pragma unroll
        for (int cc = 0; cc < 4; ++cc)
#pragma unroll
          for (int k = 0; k < 4; ++k)
            if ((q[cc][k] ^ pat) & msk)
              q[cc][k] = __hip_atomic_load(tqb + (size_t)cc * 256 + k,
                                           __ATOMIC_RELAXED, __HIP_MEMORY_SCOPE_AGENT);
        if (++guard > (1 << 20)) break;              // fail loud, not hung
      }
      asm volatile("" ::: "memory");

      // (5) strip tags -> bf16x8 fragments -> h-MFMA
#pragma unroll
      for (int cc = 0; cc < 4; ++cc) {
        union { uint32_t d[4]; bf16x8 v; } u;
#pragma unroll
        for (int k = 0; k < 4; ++k)
          u.d[k] = (uint32_t)(q[cc][k] & 0xFFFFull)
                 | (uint32_t)((q[cc][k] >> 16) & 0xFFFF0000ull);
#pragma unroll
        for (int nt = 0; nt < 4; ++nt)
          acc[nt] = __builtin_amdgcn_mfma_f32_16x16x32_bf16(u.v, breg[nt][4 + cc], acc[nt], 0, 0, 0);
      }
    }
  }
}

// ---------------------------------------------------------------------------
extern "C" void kernel_launch(void* const* d_in, const int* in_sizes, int n_in,
                              void* d_out, int out_size, void* d_ws, size_t ws_size,
                              hipStream_t stream) {
  const float* x  = (const float*)d_in[0];   // [64,512,1024]
  const float* Wx = (const float*)d_in[1];   // [1024,4096]
  const float* Wh = (const float*)d_in[2];   // [1024,4096]
  const float* b  = (const float*)d_in[3];   // [4096]
  float* out = (float*)d_out;

  char* ws = (char*)d_ws;
  uint32_t* tg  = (uint32_t*)ws;                            // 1 MB tagged-h ring
  __bf16*   wpk = (__bf16*)(ws + ((size_t)1 << 20));        // 16 MB
  __bf16*   xpk = (__bf16*)(ws + ((size_t)17 << 20));       // 64 MB  (total 81 MB)
  (void)in_sizes; (void)n_in; (void)out_size; (void)ws_size;

  // tag-poison the ring: 0xFFFF never equals a valid tag t < 512
  hipMemsetAsync(tg, 0xFF, (size_t)1 << 20, stream);

  hipLaunchKernelGGL(pack_w, dim3(4096),  dim3(256), 0, stream, Wx, Wh, wpk);
  hipLaunchKernelGGL(pack_x, dim3(16384), dim3(256), 0, stream, x, xpk);
  hipLaunchKernelGGL(lstm_scan, dim3(256), dim3(512), 0, stream,
                     xpk, wpk, b, tg, out);
}